// Round 5
// baseline (386.438 us; speedup 1.0000x reference)
//
#include <hip/hip_runtime.h>

// Problem constants (from reference setup_inputs)
#define BB    16
#define NN    8192
#define DD    128
#define MM    2048
#define TOPKK 512
#define TT    (BB*MM)     // 32768
#define BNN   (BB*NN)     // 131072

// ---------------- workspace layout (bytes) ----------------
#define WS_TAIL_AGG   0            // float[T*D]   16777216
#define WS_NEW_HID    16777216     // float[T*D]   16777216
#define WS_AGG_ATT    33554432     // double[T]    262144
#define WS_W          33816576     // double[B*384] 49152
#define WS_C          33865728     // double[B]    128
#define WS_IDX        33865856     // int[B*TOPK]  32768
#define WS_COUNTS     33898624     // int[T]       131072
#define WS_OFFSETS    34029696     // int[T+1]     131104 (padded)
#define WS_CURSOR     34160800     // int[T]       131072
#define WS_POS        34291872     // int[BNN]     524288
#define WS_LIST       34816160     // int[BNN]     524288
#define WS_ATT        35340448     // pad to 8 -> 35340448 double[BNN] 1048576
#define WS_P2         36389024     // 131072 * 1056 B = 138412032
#define P2_STRIDE_F   264          // floats per record (1056 B, 16B aligned)
#define WS_NEED_P2    (WS_P2 + (size_t)BNN * P2_STRIDE_F * 4)

// Per-batch precompute: query_b, alpha_b, w_b = Wa @ alpha_b, c_b. All f64.
__global__ __launch_bounds__(128) void k_prep(const float* __restrict__ q_head,
                                              const float* __restrict__ q_rel,
                                              const float* __restrict__ q_time,
                                              const float* __restrict__ Wq,
                                              const float* __restrict__ bq,
                                              const float* __restrict__ Wa,
                                              const float* __restrict__ ba,
                                              const float* __restrict__ Watt,
                                              const float* __restrict__ batt,
                                              double* __restrict__ w_out,   // B*384
                                              double* __restrict__ c_out) { // B
    int b = blockIdx.x;
    int d = threadIdx.x; // 0..127
    __shared__ double x_s[3*DD];
    __shared__ double alpha_s[DD];
    __shared__ double kpart[DD];
    x_s[d]        = (double)q_head[b*DD + d];
    x_s[DD + d]   = (double)q_rel [b*DD + d];
    x_s[2*DD + d] = (double)q_time[b*DD + d];
    __syncthreads();

    double acc = (double)bq[d];
    for (int k = 0; k < 3*DD; ++k) acc += x_s[k] * (double)Wq[k*DD + d];

    double W1 = (double)Watt[d];
    double W2 = (double)Watt[DD + d];
    double W3 = (double)Watt[2*DD + d];
    double a  = W1 * acc - W2 + W3;
    alpha_s[d] = a;
    kpart[d]   = acc * (W2 + W3) + (double)ba[d] * a;
    __syncthreads();

    for (int kk = d; kk < 3*DD; kk += DD) {
        double s = 0.0;
        for (int dd = 0; dd < DD; ++dd) s += (double)Wa[kk*DD + dd] * alpha_s[dd];
        w_out[b*3*DD + kk] = s;
    }
    if (d == 0) {
        double K = (double)batt[0];
        for (int dd = 0; dd < DD; ++dd) K += kpart[dd];
        c_out[b] = K;
    }
}

__global__ __launch_bounds__(256) void k_count(const int* __restrict__ tail_index,
                                               int* __restrict__ counts) {
    int i = blockIdx.x * 256 + threadIdx.x;
    if (i < BNN) atomicAdd(&counts[tail_index[i]], 1);
}

// Single-block exclusive scan of counts[T] -> offsets, cursor. 1024 thr x 32.
__global__ __launch_bounds__(1024) void k_scan(const int* __restrict__ counts,
                                               int* __restrict__ offsets,
                                               int* __restrict__ cursor) {
    __shared__ int s[1024];
    int tid = threadIdx.x;
    int base = tid * 32;
    int sum = 0;
    for (int j = 0; j < 32; ++j) sum += counts[base + j];
    s[tid] = sum;
    __syncthreads();
    for (int off = 1; off < 1024; off <<= 1) {
        int v = (tid >= off) ? s[tid - off] : 0;
        __syncthreads();
        s[tid] += v;
        __syncthreads();
    }
    int run = s[tid] - sum;
    for (int j = 0; j < 32; ++j) {
        int c = counts[base + j];
        offsets[base + j] = run;
        cursor [base + j] = run;
        run += c;
    }
    if (tid == 1023) offsets[TT] = run;
}

// pos[row] = slot in segment-sorted order; list[slot] = row | (localseg<<27)
__global__ __launch_bounds__(256) void k_fill(const int* __restrict__ tail_index,
                                              int* __restrict__ cursor,
                                              int* __restrict__ pos,
                                              int* __restrict__ list) {
    int i = blockIdx.x * 256 + threadIdx.x;
    if (i < BNN) {
        int t = tail_index[i];
        int p = atomicAdd(&cursor[t], 1);
        pos[i]  = p;
        list[p] = i | ((t & 15) << 27);
    }
}

// ---------------- Phase A: streaming att compute ----------------
// Wave handles 2 consecutive rows (one per 32-lane half). Fully coalesced.
// SCATTER=1: also writes packed record {m, h, att, seg} to P2[pos[row]].
template<int SCATTER>
__global__ __launch_bounds__(256) void k_att(const float* __restrict__ r_n,
                                             const float* __restrict__ t_n,
                                             const float* __restrict__ tm_n,
                                             const float* __restrict__ hidden,
                                             const float* __restrict__ q_head,
                                             const float* __restrict__ Wrule,
                                             const float* __restrict__ brule,
                                             const int* __restrict__ tail_index,
                                             const int* __restrict__ pos,
                                             const double* __restrict__ w_all,
                                             const double* __restrict__ c_all,
                                             double* __restrict__ attArr,
                                             float* __restrict__ P2) {
    const int wave = threadIdx.x >> 6;
    const int lane = threadIdx.x & 63;
    const int half = lane >> 5;
    const int sl   = lane & 31;
    const int d0   = 4 * sl;
    const int row  = (blockIdx.x * 4 + wave) * 2 + half;
    const int b    = row >> 13;

    const double* w = w_all + b * 3 * DD;
    float w0[4], w1[4], w2[4];
    #pragma unroll
    for (int j = 0; j < 4; ++j) {
        w0[j] = (float)w[d0 + j];
        w1[j] = (float)w[DD + d0 + j];
        w2[j] = (float)w[2*DD + d0 + j];
    }
    const float4 wr = *(const float4*)(Wrule + d0);
    const double cb = c_all[b];
    const double br = (double)brule[0];

    long long base = (long long)row * DD + d0;
    float4 rv = *(const float4*)(r_n    + base);
    float4 tv = *(const float4*)(t_n    + base);
    float4 mv = *(const float4*)(tm_n   + base);
    float4 hv = *(const float4*)(hidden + base);

    double z1 = (double)rv.x*(double)w0[0] + (double)rv.y*(double)w0[1]
              + (double)rv.z*(double)w0[2] + (double)rv.w*(double)w0[3]
              + (double)tv.x*(double)w1[0] + (double)tv.y*(double)w1[1]
              + (double)tv.z*(double)w1[2] + (double)tv.w*(double)w1[3]
              + (double)mv.x*(double)w2[0] + (double)mv.y*(double)w2[1]
              + (double)mv.z*(double)w2[2] + (double)mv.w*(double)w2[3];
    double z2 = (double)hv.x*(double)wr.x + (double)hv.y*(double)wr.y
              + (double)hv.z*(double)wr.z + (double)hv.w*(double)wr.w;
    #pragma unroll
    for (int o = 16; o > 0; o >>= 1) {
        z1 += __shfl_xor(z1, o);
        z2 += __shfl_xor(z2, o);
    }
    // parity exp dedup (validated R4)
    double x  = (lane & 1) ? (z2 + br) : (z1 + cb);
    double ex = exp(-x);
    double exo = __shfl_xor(ex, 1);
    double att_d = 0.5 * (2.0 + ex + exo) / ((1.0 + ex) * (1.0 + exo));

    if (SCATTER) {
        int t  = tail_index[row];
        int p  = pos[row];
        float* rec = P2 + (size_t)p * P2_STRIDE_F;
        float4 qh = *(const float4*)(q_head + b*DD + d0);
        float4 m4;
        m4.x = qh.x + rv.x + mv.x; m4.y = qh.y + rv.y + mv.y;
        m4.z = qh.z + rv.z + mv.z; m4.w = qh.w + rv.w + mv.w;
        *(float4*)(rec + d0)       = m4;
        *(float4*)(rec + DD + d0)  = hv;
        if (sl == 0) {
            *(double*)(rec + 2*DD) = att_d;
            ((int*)rec)[2*DD + 2]  = t & 15;
        }
    } else {
        if (sl == 0) attArr[row] = att_d;
    }
}

// ---------------- Phase B: segment accumulation ----------------
// Block owns 16 consecutive segments; entries are contiguous in sorted order.
// LDS accumulators, f32 LDS atomics for msg/hidden, f64 for att sums.
// Streaming variant: reads packed P2 records sequentially.
__global__ __launch_bounds__(256) void k_aggS(const float* __restrict__ P2,
                                              const float* __restrict__ tail_emd,
                                              const int* __restrict__ offsets,
                                              float* __restrict__ tail_agg,
                                              float* __restrict__ new_hidden,
                                              double* __restrict__ agg_att) {
    __shared__ float  accM[16][DD];
    __shared__ float  accH[16][DD];
    __shared__ double accA[16];
    const int tid = threadIdx.x;
    const int hw  = tid >> 5;
    const int sl  = tid & 31;
    const int d0  = 4 * sl;
    const int s0  = blockIdx.x * 16;

    for (int i = tid; i < 16*DD; i += 256) { ((float*)accM)[i] = 0.f; ((float*)accH)[i] = 0.f; }
    if (tid < 16) accA[tid] = 0.0;
    __syncthreads();

    const int start = offsets[s0];
    const int end   = offsets[s0 + 16];
    for (int e = start + hw; e < end; e += 8) {
        const float* rec = P2 + (size_t)e * P2_STRIDE_F;
        float4 m4 = *(const float4*)(rec + d0);
        float4 h4 = *(const float4*)(rec + DD + d0);
        double attd = *(const double*)(rec + 2*DD);
        int local   = ((const int*)rec)[2*DD + 2];
        float att   = (float)attd;
        atomicAdd(&accM[local][d0+0], att*m4.x);
        atomicAdd(&accM[local][d0+1], att*m4.y);
        atomicAdd(&accM[local][d0+2], att*m4.z);
        atomicAdd(&accM[local][d0+3], att*m4.w);
        atomicAdd(&accH[local][d0+0], h4.x);
        atomicAdd(&accH[local][d0+1], h4.y);
        atomicAdd(&accH[local][d0+2], h4.z);
        atomicAdd(&accH[local][d0+3], h4.w);
        if (sl == 0) atomicAdd(&accA[local], attd);
    }
    __syncthreads();
    for (int i = tid; i < 16*DD; i += 256) {
        int seg = i >> 7, d = i & (DD-1);
        long long o = (long long)(s0 + seg) * DD + d;
        tail_agg[o]   = tail_emd[o] + accM[seg][d];
        new_hidden[o] = accH[seg][d];
    }
    if (tid < 16) agg_att[s0 + tid] = accA[tid];
}

// Gather variant: reads r/tm/hidden rows via list + att array.
__global__ __launch_bounds__(256) void k_aggG(const float* __restrict__ r_n,
                                              const float* __restrict__ tm_n,
                                              const float* __restrict__ hidden,
                                              const float* __restrict__ q_head,
                                              const float* __restrict__ tail_emd,
                                              const int* __restrict__ offsets,
                                              const int* __restrict__ list,
                                              const double* __restrict__ attArr,
                                              float* __restrict__ tail_agg,
                                              float* __restrict__ new_hidden,
                                              double* __restrict__ agg_att) {
    __shared__ float  accM[16][DD];
    __shared__ float  accH[16][DD];
    __shared__ double accA[16];
    const int tid = threadIdx.x;
    const int hw  = tid >> 5;
    const int sl  = tid & 31;
    const int d0  = 4 * sl;
    const int s0  = blockIdx.x * 16;
    const int b   = s0 >> 11;     // all 16 segs share one batch (2048 % 16 == 0)

    for (int i = tid; i < 16*DD; i += 256) { ((float*)accM)[i] = 0.f; ((float*)accH)[i] = 0.f; }
    if (tid < 16) accA[tid] = 0.0;
    __syncthreads();

    const float4 qh = *(const float4*)(q_head + b*DD + d0);
    const int start = offsets[s0];
    const int end   = offsets[s0 + 16];
    for (int e = start + hw; e < end; e += 8) {
        int v     = list[e];
        int row   = v & 0x07FFFFFF;
        int local = v >> 27;
        long long base = (long long)row * DD + d0;
        float4 rv = *(const float4*)(r_n    + base);
        float4 mv = *(const float4*)(tm_n   + base);
        float4 h4 = *(const float4*)(hidden + base);
        double attd = attArr[row];
        float att   = (float)attd;
        atomicAdd(&accM[local][d0+0], att*(qh.x + rv.x + mv.x));
        atomicAdd(&accM[local][d0+1], att*(qh.y + rv.y + mv.y));
        atomicAdd(&accM[local][d0+2], att*(qh.z + rv.z + mv.z));
        atomicAdd(&accM[local][d0+3], att*(qh.w + rv.w + mv.w));
        atomicAdd(&accH[local][d0+0], h4.x);
        atomicAdd(&accH[local][d0+1], h4.y);
        atomicAdd(&accH[local][d0+2], h4.z);
        atomicAdd(&accH[local][d0+3], h4.w);
        if (sl == 0) atomicAdd(&accA[local], attd);
    }
    __syncthreads();
    for (int i = tid; i < 16*DD; i += 256) {
        int seg = i >> 7, d = i & (DD-1);
        long long o = (long long)(s0 + seg) * DD + d;
        tail_agg[o]   = tail_emd[o] + accM[seg][d];
        new_hidden[o] = accH[seg][d];
    }
    if (tid < 16) agg_att[s0 + tid] = accA[tid];
}

// Per-batch exact top-k: bitonic sort of M=2048 (value desc, index asc).
__global__ __launch_bounds__(1024) void k_topk(const double* __restrict__ agg_att,
                                               const int* __restrict__ tail_nodes,
                                               int* __restrict__ idx_out,
                                               float* __restrict__ out_nodes) {
    int b = blockIdx.x;
    __shared__ double v[MM];
    __shared__ int    id[MM];
    for (int i = threadIdx.x; i < MM; i += blockDim.x) {
        v[i]  = agg_att[b*MM + i];
        id[i] = i;
    }
    __syncthreads();
    for (int k = 2; k <= MM; k <<= 1) {
        for (int j = k >> 1; j > 0; j >>= 1) {
            for (int i = threadIdx.x; i < MM; i += blockDim.x) {
                int ixj = i ^ j;
                if (ixj > i) {
                    double va = v[i], vb = v[ixj];
                    int    ia = id[i], ib = id[ixj];
                    bool aBeforeB = (va > vb) || (va == vb && ia < ib);
                    bool wantBefore = ((i & k) == 0);
                    if (wantBefore != aBeforeB) {
                        v[i] = vb; v[ixj] = va;
                        id[i] = ib; id[ixj] = ia;
                    }
                }
            }
            __syncthreads();
        }
    }
    for (int r = threadIdx.x; r < TOPKK; r += blockDim.x) {
        int t = b * MM + id[r];
        idx_out[b*TOPKK + r] = t;
        out_nodes[(b*TOPKK + r)*2 + 0] = (float)tail_nodes[t*3 + 1];
        out_nodes[(b*TOPKK + r)*2 + 1] = (float)tail_nodes[t*3 + 2];
    }
}

// Epilogue: emd = tail_agg[idx] @ Wout + bout ; hid = new_hidden[idx]
#define ROWS_PER_BLK 8
__global__ __launch_bounds__(128) void k_out(const float* __restrict__ tail_agg,
                                             const float* __restrict__ new_hidden,
                                             const float* __restrict__ Wout,
                                             const float* __restrict__ bout,
                                             const int* __restrict__ idx_ws,
                                             float* __restrict__ out_emd,
                                             float* __restrict__ out_hid) {
    int c = threadIdx.x;
    int pair0 = blockIdx.x * ROWS_PER_BLK;
    __shared__ float a_s[ROWS_PER_BLK][DD];
    int ts[ROWS_PER_BLK];
    #pragma unroll
    for (int j = 0; j < ROWS_PER_BLK; ++j) {
        ts[j] = idx_ws[pair0 + j];
        a_s[j][c] = tail_agg[(long long)ts[j] * DD + c];
    }
    __syncthreads();
    float acc[ROWS_PER_BLK];
    float bc = bout[c];
    #pragma unroll
    for (int j = 0; j < ROWS_PER_BLK; ++j) acc[j] = bc;
    for (int d = 0; d < DD; ++d) {
        float wv = Wout[d*DD + c];
        #pragma unroll
        for (int j = 0; j < ROWS_PER_BLK; ++j)
            acc[j] = fmaf(a_s[j][d], wv, acc[j]);
    }
    #pragma unroll
    for (int j = 0; j < ROWS_PER_BLK; ++j) {
        long long p = (long long)(pair0 + j) * DD + c;
        out_emd[p] = acc[j];
        out_hid[p] = new_hidden[(long long)ts[j] * DD + c];
    }
}

extern "C" void kernel_launch(void* const* d_in, const int* in_sizes, int n_in,
                              void* d_out, int out_size, void* d_ws, size_t ws_size,
                              hipStream_t stream) {
    const float* q_head   = (const float*)d_in[0];
    const float* q_rel    = (const float*)d_in[1];
    const float* q_time   = (const float*)d_in[2];
    const float* r_n      = (const float*)d_in[3];
    const float* t_n      = (const float*)d_in[4];
    const float* tm_n     = (const float*)d_in[5];
    const float* hidden   = (const float*)d_in[6];
    const float* tail_emd = (const float*)d_in[7];
    const int*   tail_index = (const int*)d_in[8];
    const int*   tail_nodes = (const int*)d_in[9];
    const float* Wq   = (const float*)d_in[10];
    const float* bq   = (const float*)d_in[11];
    const float* Wa   = (const float*)d_in[12];
    const float* ba   = (const float*)d_in[13];
    const float* Watt = (const float*)d_in[14];
    const float* batt = (const float*)d_in[15];
    const float* Wrule = (const float*)d_in[16];
    const float* brule = (const float*)d_in[17];
    const float* Wout = (const float*)d_in[18];
    const float* bout = (const float*)d_in[19];

    char* ws = (char*)d_ws;
    float*  tail_agg   = (float*) (ws + WS_TAIL_AGG);
    float*  new_hidden = (float*) (ws + WS_NEW_HID);
    double* agg_att    = (double*)(ws + WS_AGG_ATT);
    double* w_all      = (double*)(ws + WS_W);
    double* c_all      = (double*)(ws + WS_C);
    int*    idx_ws     = (int*)   (ws + WS_IDX);
    int*    counts     = (int*)   (ws + WS_COUNTS);
    int*    offsets    = (int*)   (ws + WS_OFFSETS);
    int*    cursor     = (int*)   (ws + WS_CURSOR);
    int*    pos        = (int*)   (ws + WS_POS);
    int*    list       = (int*)   (ws + WS_LIST);
    double* attArr     = (double*)(ws + WS_ATT);
    float*  P2         = (float*) (ws + WS_P2);

    const bool big = (ws_size >= WS_NEED_P2);

    float* out       = (float*)d_out;
    float* out_nodes = out;                      // B*TOPK*2
    float* out_emd   = out + BB*TOPKK*2;         // B*TOPK*D
    float* out_hid   = out_emd + BB*TOPKK*DD;    // B*TOPK*D

    hipMemsetAsync(counts, 0, TT * sizeof(int), stream);
    hipLaunchKernelGGL(k_prep, dim3(BB), dim3(DD), 0, stream,
                       q_head, q_rel, q_time, Wq, bq, Wa, ba, Watt, batt,
                       w_all, c_all);
    hipLaunchKernelGGL(k_count, dim3(BNN/256), dim3(256), 0, stream,
                       tail_index, counts);
    hipLaunchKernelGGL(k_scan, dim3(1), dim3(1024), 0, stream,
                       counts, offsets, cursor);
    hipLaunchKernelGGL(k_fill, dim3(BNN/256), dim3(256), 0, stream,
                       tail_index, cursor, pos, list);
    if (big) {
        hipLaunchKernelGGL((k_att<1>), dim3(BNN/8), dim3(256), 0, stream,
                           r_n, t_n, tm_n, hidden, q_head, Wrule, brule,
                           tail_index, pos, w_all, c_all, attArr, P2);
        hipLaunchKernelGGL(k_aggS, dim3(TT/16), dim3(256), 0, stream,
                           P2, tail_emd, offsets, tail_agg, new_hidden, agg_att);
    } else {
        hipLaunchKernelGGL((k_att<0>), dim3(BNN/8), dim3(256), 0, stream,
                           r_n, t_n, tm_n, hidden, q_head, Wrule, brule,
                           tail_index, pos, w_all, c_all, attArr, P2);
        hipLaunchKernelGGL(k_aggG, dim3(TT/16), dim3(256), 0, stream,
                           r_n, tm_n, hidden, q_head, tail_emd, offsets, list,
                           attArr, tail_agg, new_hidden, agg_att);
    }
    hipLaunchKernelGGL(k_topk, dim3(BB), dim3(1024), 0, stream,
                       agg_att, tail_nodes, idx_ws, out_nodes);
    hipLaunchKernelGGL(k_out, dim3(BB*TOPKK/ROWS_PER_BLK), dim3(DD), 0, stream,
                       tail_agg, new_hidden, Wout, bout, idx_ws,
                       out_emd, out_hid);
}

// Round 6
// 178.116 us; speedup vs baseline: 2.1696x; 2.1696x over previous
//
#include <hip/hip_runtime.h>

// Problem constants (from reference setup_inputs)
#define BB    16
#define NN    8192
#define DD    128
#define MM    2048
#define TOPKK 512
#define TT    (BB*MM)     // 32768
#define BNN   (BB*NN)     // 131072
#define WINS  (BB*TOPKK)  // 8192

// ---------------- workspace layout (bytes) ----------------
#define WS_TAW     0           // float[WINS*DD]   4194304
#define WS_AGG     4194304     // double[TT]       262144
#define WS_W       4456448     // double[B*384]    49152
#define WS_C       4505600     // double[B]        128
#define WS_IDX     4505728     // int[WINS]        32768
#define WS_COUNTS  4538496     // int[TT]          131072
#define WS_OFFSETS 4669568     // int[TT+1]        131104 (padded)
#define WS_CURSOR  4800704     // int[TT]          131072
#define WS_LIST    4931776     // int[BNN]         524288
#define WS_ATT     5456064     // double[BNN]      1048576  (8-aligned)

// Per-batch precompute: query_b, alpha_b, w_b = Wa @ alpha_b, c_b. All f64.
__global__ __launch_bounds__(128) void k_prep(const float* __restrict__ q_head,
                                              const float* __restrict__ q_rel,
                                              const float* __restrict__ q_time,
                                              const float* __restrict__ Wq,
                                              const float* __restrict__ bq,
                                              const float* __restrict__ Wa,
                                              const float* __restrict__ ba,
                                              const float* __restrict__ Watt,
                                              const float* __restrict__ batt,
                                              double* __restrict__ w_out,   // B*384
                                              double* __restrict__ c_out) { // B
    int b = blockIdx.x;
    int d = threadIdx.x; // 0..127
    __shared__ double x_s[3*DD];
    __shared__ double alpha_s[DD];
    __shared__ double kpart[DD];
    x_s[d]        = (double)q_head[b*DD + d];
    x_s[DD + d]   = (double)q_rel [b*DD + d];
    x_s[2*DD + d] = (double)q_time[b*DD + d];
    __syncthreads();

    double acc = (double)bq[d];
    for (int k = 0; k < 3*DD; ++k) acc += x_s[k] * (double)Wq[k*DD + d];

    double W1 = (double)Watt[d];
    double W2 = (double)Watt[DD + d];
    double W3 = (double)Watt[2*DD + d];
    double a  = W1 * acc - W2 + W3;
    alpha_s[d] = a;
    kpart[d]   = acc * (W2 + W3) + (double)ba[d] * a;
    __syncthreads();

    for (int kk = d; kk < 3*DD; kk += DD) {
        double s = 0.0;
        for (int dd = 0; dd < DD; ++dd) s += (double)Wa[kk*DD + dd] * alpha_s[dd];
        w_out[b*3*DD + kk] = s;
    }
    if (d == 0) {
        double K = (double)batt[0];
        for (int dd = 0; dd < DD; ++dd) K += kpart[dd];
        c_out[b] = K;
    }
}

__global__ __launch_bounds__(256) void k_count(const int* __restrict__ tail_index,
                                               int* __restrict__ counts) {
    int i = blockIdx.x * 256 + threadIdx.x;
    if (i < BNN) atomicAdd(&counts[tail_index[i]], 1);
}

// Single-block exclusive scan of counts[T] -> offsets, cursor. 1024 thr x 32.
__global__ __launch_bounds__(1024) void k_scan(const int* __restrict__ counts,
                                               int* __restrict__ offsets,
                                               int* __restrict__ cursor) {
    __shared__ int s[1024];
    int tid = threadIdx.x;
    int base = tid * 32;
    int sum = 0;
    for (int j = 0; j < 32; ++j) sum += counts[base + j];
    s[tid] = sum;
    __syncthreads();
    for (int off = 1; off < 1024; off <<= 1) {
        int v = (tid >= off) ? s[tid - off] : 0;
        __syncthreads();
        s[tid] += v;
        __syncthreads();
    }
    int run = s[tid] - sum;
    for (int j = 0; j < 32; ++j) {
        int c = counts[base + j];
        offsets[base + j] = run;
        cursor [base + j] = run;
        run += c;
    }
    if (tid == 1023) offsets[TT] = run;
}

__global__ __launch_bounds__(256) void k_fill(const int* __restrict__ tail_index,
                                              int* __restrict__ cursor,
                                              int* __restrict__ list) {
    int i = blockIdx.x * 256 + threadIdx.x;
    if (i < BNN) {
        int t = tail_index[i];
        int p = atomicAdd(&cursor[t], 1);
        list[p] = i;
    }
}

// ---------------- Phase A: streaming att + agg_att ----------------
// One row per 32-lane half-wave (float4/lane = 128 dims). No loop, no
// scattered bulk writes: outputs are att[row] (8B) and one f64 hardware
// atomic into agg_att[t] per row.
__global__ __launch_bounds__(256) void k_att(const float* __restrict__ r_n,
                                             const float* __restrict__ t_n,
                                             const float* __restrict__ tm_n,
                                             const float* __restrict__ hidden,
                                             const float* __restrict__ Wrule,
                                             const float* __restrict__ brule,
                                             const int* __restrict__ tail_index,
                                             const double* __restrict__ w_all,
                                             const double* __restrict__ c_all,
                                             double* __restrict__ attArr,
                                             double* __restrict__ agg_att) {
    const int wave = threadIdx.x >> 6;
    const int lane = threadIdx.x & 63;
    const int half = lane >> 5;
    const int sl   = lane & 31;
    const int d0   = 4 * sl;
    const int row  = (blockIdx.x * 4 + wave) * 2 + half;
    const int b    = row >> 13;

    const double* w = w_all + b * 3 * DD;
    float w0[4], w1[4], w2[4];
    #pragma unroll
    for (int j = 0; j < 4; ++j) {
        w0[j] = (float)w[d0 + j];
        w1[j] = (float)w[DD + d0 + j];
        w2[j] = (float)w[2*DD + d0 + j];
    }
    const float4 wr = *(const float4*)(Wrule + d0);
    const double cb = c_all[b];
    const double br = (double)brule[0];

    long long base = (long long)row * DD + d0;
    float4 rv = *(const float4*)(r_n    + base);
    float4 tv = *(const float4*)(t_n    + base);
    float4 mv = *(const float4*)(tm_n   + base);
    float4 hv = *(const float4*)(hidden + base);

    double z1 = (double)rv.x*(double)w0[0] + (double)rv.y*(double)w0[1]
              + (double)rv.z*(double)w0[2] + (double)rv.w*(double)w0[3]
              + (double)tv.x*(double)w1[0] + (double)tv.y*(double)w1[1]
              + (double)tv.z*(double)w1[2] + (double)tv.w*(double)w1[3]
              + (double)mv.x*(double)w2[0] + (double)mv.y*(double)w2[1]
              + (double)mv.z*(double)w2[2] + (double)mv.w*(double)w2[3];
    double z2 = (double)hv.x*(double)wr.x + (double)hv.y*(double)wr.y
              + (double)hv.z*(double)wr.z + (double)hv.w*(double)wr.w;
    #pragma unroll
    for (int o = 16; o > 0; o >>= 1) {
        z1 += __shfl_xor(z1, o);
        z2 += __shfl_xor(z2, o);
    }
    // parity exp dedup: even lanes exp(-(z1+cb)), odd lanes exp(-(z2+br))
    double x  = (lane & 1) ? (z2 + br) : (z1 + cb);
    double ex = exp(-x);
    double exo = __shfl_xor(ex, 1);
    double att_d = 0.5 * (2.0 + ex + exo) / ((1.0 + ex) * (1.0 + exo));

    if (sl == 0) {
        attArr[row] = att_d;
        int t = tail_index[row];
        unsafeAtomicAdd(&agg_att[t], att_d);
    }
}

// Per-batch exact top-k: bitonic sort of M=2048 (value desc, index asc).
__global__ __launch_bounds__(1024) void k_topk(const double* __restrict__ agg_att,
                                               const int* __restrict__ tail_nodes,
                                               int* __restrict__ idx_out,
                                               float* __restrict__ out_nodes) {
    int b = blockIdx.x;
    __shared__ double v[MM];
    __shared__ int    id[MM];
    for (int i = threadIdx.x; i < MM; i += blockDim.x) {
        v[i]  = agg_att[b*MM + i];
        id[i] = i;
    }
    __syncthreads();
    for (int k = 2; k <= MM; k <<= 1) {
        for (int j = k >> 1; j > 0; j >>= 1) {
            for (int i = threadIdx.x; i < MM; i += blockDim.x) {
                int ixj = i ^ j;
                if (ixj > i) {
                    double va = v[i], vb = v[ixj];
                    int    ia = id[i], ib = id[ixj];
                    bool aBeforeB = (va > vb) || (va == vb && ia < ib);
                    bool wantBefore = ((i & k) == 0);
                    if (wantBefore != aBeforeB) {
                        v[i] = vb; v[ixj] = va;
                        id[i] = ib; id[ixj] = ia;
                    }
                }
            }
            __syncthreads();
        }
    }
    for (int r = threadIdx.x; r < TOPKK; r += blockDim.x) {
        int t = b * MM + id[r];
        idx_out[b*TOPKK + r] = t;
        out_nodes[(b*TOPKK + r)*2 + 0] = (float)tail_nodes[t*3 + 1];
        out_nodes[(b*TOPKK + r)*2 + 1] = (float)tail_nodes[t*3 + 2];
    }
}

// ---------------- Phase C: aggregate ONLY winning segments ----------------
// One half-wave per winner; register accumulation; writes compact taw and
// out_hid directly. ~25% of rows gathered, no atomics, no chain.
__global__ __launch_bounds__(256) void k_aggW(const float* __restrict__ r_n,
                                              const float* __restrict__ tm_n,
                                              const float* __restrict__ hidden,
                                              const float* __restrict__ q_head,
                                              const float* __restrict__ tail_emd,
                                              const int* __restrict__ offsets,
                                              const int* __restrict__ list,
                                              const double* __restrict__ attArr,
                                              const int* __restrict__ idx_ws,
                                              float* __restrict__ taw,
                                              float* __restrict__ out_hid) {
    const int hw = threadIdx.x >> 5;
    const int sl = threadIdx.x & 31;
    const int d0 = 4 * sl;
    const int wi = blockIdx.x * 8 + hw;      // winner index, rank order
    const int t  = idx_ws[wi];
    const int b  = t >> 11;                  // t / M

    const float4 qh = *(const float4*)(q_head + b*DD + d0);
    const int start = offsets[t];
    const int end   = offsets[t + 1];

    float p0 = 0.f, p1 = 0.f, p2 = 0.f, p3 = 0.f;
    float h0 = 0.f, h1 = 0.f, h2 = 0.f, h3 = 0.f;
    double asum = 0.0;

    for (int e = start; e < end; ++e) {
        int row = list[e];
        long long base = (long long)row * DD + d0;
        float4 rv = *(const float4*)(r_n    + base);
        float4 mv = *(const float4*)(tm_n   + base);
        float4 hv = *(const float4*)(hidden + base);
        double attd = attArr[row];
        float  att  = (float)attd;
        p0 += att * (rv.x + mv.x); p1 += att * (rv.y + mv.y);
        p2 += att * (rv.z + mv.z); p3 += att * (rv.w + mv.w);
        h0 += hv.x; h1 += hv.y; h2 += hv.z; h3 += hv.w;
        asum += attd;
    }

    float A = (float)asum;
    long long ot = (long long)t  * DD + d0;
    long long ow = (long long)wi * DD + d0;
    float4 te = *(const float4*)(tail_emd + ot);
    float4 ta;
    ta.x = te.x + A*qh.x + p0; ta.y = te.y + A*qh.y + p1;
    ta.z = te.z + A*qh.z + p2; ta.w = te.w + A*qh.w + p3;
    *(float4*)(taw + ow) = ta;
    float4 nh; nh.x = h0; nh.y = h1; nh.z = h2; nh.w = h3;
    *(float4*)(out_hid + ow) = nh;
}

// Epilogue: emd = taw @ Wout + bout (compact, contiguous rows).
#define ROWS_PER_BLK 8
__global__ __launch_bounds__(128) void k_out(const float* __restrict__ taw,
                                             const float* __restrict__ Wout,
                                             const float* __restrict__ bout,
                                             float* __restrict__ out_emd) {
    int c = threadIdx.x;
    int pair0 = blockIdx.x * ROWS_PER_BLK;
    __shared__ float a_s[ROWS_PER_BLK][DD];
    #pragma unroll
    for (int j = 0; j < ROWS_PER_BLK; ++j)
        a_s[j][c] = taw[(long long)(pair0 + j) * DD + c];
    __syncthreads();
    float acc[ROWS_PER_BLK];
    float bc = bout[c];
    #pragma unroll
    for (int j = 0; j < ROWS_PER_BLK; ++j) acc[j] = bc;
    for (int d = 0; d < DD; ++d) {
        float wv = Wout[d*DD + c];
        #pragma unroll
        for (int j = 0; j < ROWS_PER_BLK; ++j)
            acc[j] = fmaf(a_s[j][d], wv, acc[j]);
    }
    #pragma unroll
    for (int j = 0; j < ROWS_PER_BLK; ++j)
        out_emd[(long long)(pair0 + j) * DD + c] = acc[j];
}

extern "C" void kernel_launch(void* const* d_in, const int* in_sizes, int n_in,
                              void* d_out, int out_size, void* d_ws, size_t ws_size,
                              hipStream_t stream) {
    const float* q_head   = (const float*)d_in[0];
    const float* q_rel    = (const float*)d_in[1];
    const float* q_time   = (const float*)d_in[2];
    const float* r_n      = (const float*)d_in[3];
    const float* t_n      = (const float*)d_in[4];
    const float* tm_n     = (const float*)d_in[5];
    const float* hidden   = (const float*)d_in[6];
    const float* tail_emd = (const float*)d_in[7];
    const int*   tail_index = (const int*)d_in[8];
    const int*   tail_nodes = (const int*)d_in[9];
    const float* Wq   = (const float*)d_in[10];
    const float* bq   = (const float*)d_in[11];
    const float* Wa   = (const float*)d_in[12];
    const float* ba   = (const float*)d_in[13];
    const float* Watt = (const float*)d_in[14];
    const float* batt = (const float*)d_in[15];
    const float* Wrule = (const float*)d_in[16];
    const float* brule = (const float*)d_in[17];
    const float* Wout = (const float*)d_in[18];
    const float* bout = (const float*)d_in[19];

    char* ws = (char*)d_ws;
    float*  taw     = (float*) (ws + WS_TAW);
    double* agg_att = (double*)(ws + WS_AGG);
    double* w_all   = (double*)(ws + WS_W);
    double* c_all   = (double*)(ws + WS_C);
    int*    idx_ws  = (int*)   (ws + WS_IDX);
    int*    counts  = (int*)   (ws + WS_COUNTS);
    int*    offsets = (int*)   (ws + WS_OFFSETS);
    int*    cursor  = (int*)   (ws + WS_CURSOR);
    int*    list    = (int*)   (ws + WS_LIST);
    double* attArr  = (double*)(ws + WS_ATT);

    float* out       = (float*)d_out;
    float* out_nodes = out;                      // B*TOPK*2
    float* out_emd   = out + BB*TOPKK*2;         // B*TOPK*D
    float* out_hid   = out_emd + BB*TOPKK*DD;    // B*TOPK*D

    hipMemsetAsync(counts, 0, TT * sizeof(int), stream);
    hipMemsetAsync(agg_att, 0, TT * sizeof(double), stream);
    hipLaunchKernelGGL(k_prep, dim3(BB), dim3(DD), 0, stream,
                       q_head, q_rel, q_time, Wq, bq, Wa, ba, Watt, batt,
                       w_all, c_all);
    hipLaunchKernelGGL(k_count, dim3(BNN/256), dim3(256), 0, stream,
                       tail_index, counts);
    hipLaunchKernelGGL(k_scan, dim3(1), dim3(1024), 0, stream,
                       counts, offsets, cursor);
    hipLaunchKernelGGL(k_fill, dim3(BNN/256), dim3(256), 0, stream,
                       tail_index, cursor, list);
    hipLaunchKernelGGL(k_att, dim3(BNN/8), dim3(256), 0, stream,
                       r_n, t_n, tm_n, hidden, Wrule, brule,
                       tail_index, w_all, c_all, attArr, agg_att);
    hipLaunchKernelGGL(k_topk, dim3(BB), dim3(1024), 0, stream,
                       agg_att, tail_nodes, idx_ws, out_nodes);
    hipLaunchKernelGGL(k_aggW, dim3(WINS/8), dim3(256), 0, stream,
                       r_n, tm_n, hidden, q_head, tail_emd,
                       offsets, list, attArr, idx_ws, taw, out_hid);
    hipLaunchKernelGGL(k_out, dim3(WINS/ROWS_PER_BLK), dim3(DD), 0, stream,
                       taw, Wout, bout, out_emd);
}

// Round 7
// 173.921 us; speedup vs baseline: 2.2219x; 1.0241x over previous
//
#include <hip/hip_runtime.h>

// Problem constants (from reference setup_inputs)
#define BB    16
#define NN    8192
#define DD    128
#define MM    2048
#define TOPKK 512
#define TT    (BB*MM)     // 32768
#define BNN   (BB*NN)     // 131072
#define WINS  (BB*TOPKK)  // 8192

// ---------------- workspace layout (bytes) ----------------
#define WS_TAW     0           // float[WINS*DD]   4194304
#define WS_COUNTS  4194304     // int[TT]          131072
#define WS_AGG     4325376     // double[TT]       262144   (adjacent to counts: one memset)
#define WS_W       4587520     // double[B*384]    49152
#define WS_C       4636672     // double[B]        128
#define WS_IDX     4636800     // int[WINS]        32768
#define WS_OFFSETS 4669568     // int[TT+1]        131136 (padded)
#define WS_CURSOR  4800704     // int[TT]          131072
#define WS_LIST    4931776     // int[BNN]         524288
#define WS_ATT     5456064     // double[BNN]      1048576  (8-aligned)

// Per-batch precompute: query_b, alpha_b, w_b = Wa @ alpha_b, c_b. All f64.
__global__ __launch_bounds__(128) void k_prep(const float* __restrict__ q_head,
                                              const float* __restrict__ q_rel,
                                              const float* __restrict__ q_time,
                                              const float* __restrict__ Wq,
                                              const float* __restrict__ bq,
                                              const float* __restrict__ Wa,
                                              const float* __restrict__ ba,
                                              const float* __restrict__ Watt,
                                              const float* __restrict__ batt,
                                              double* __restrict__ w_out,   // B*384
                                              double* __restrict__ c_out) { // B
    int b = blockIdx.x;
    int d = threadIdx.x; // 0..127
    __shared__ double x_s[3*DD];
    __shared__ double alpha_s[DD];
    __shared__ double kpart[DD];
    x_s[d]        = (double)q_head[b*DD + d];
    x_s[DD + d]   = (double)q_rel [b*DD + d];
    x_s[2*DD + d] = (double)q_time[b*DD + d];
    __syncthreads();

    double acc = (double)bq[d];
    for (int k = 0; k < 3*DD; ++k) acc += x_s[k] * (double)Wq[k*DD + d];

    double W1 = (double)Watt[d];
    double W2 = (double)Watt[DD + d];
    double W3 = (double)Watt[2*DD + d];
    double a  = W1 * acc - W2 + W3;
    alpha_s[d] = a;
    kpart[d]   = acc * (W2 + W3) + (double)ba[d] * a;
    __syncthreads();

    for (int kk = d; kk < 3*DD; kk += DD) {
        double s = 0.0;
        for (int dd = 0; dd < DD; ++dd) s += (double)Wa[kk*DD + dd] * alpha_s[dd];
        w_out[b*3*DD + kk] = s;
    }
    if (d == 0) {
        double K = (double)batt[0];
        for (int dd = 0; dd < DD; ++dd) K += kpart[dd];
        c_out[b] = K;
    }
}

__global__ __launch_bounds__(256) void k_count(const int* __restrict__ tail_index,
                                               int* __restrict__ counts) {
    int i = blockIdx.x * 256 + threadIdx.x;
    if (i < BNN) atomicAdd(&counts[tail_index[i]], 1);
}

// Single-block exclusive scan of counts[T] -> offsets, cursor. 1024 thr x 32.
__global__ __launch_bounds__(1024) void k_scan(const int* __restrict__ counts,
                                               int* __restrict__ offsets,
                                               int* __restrict__ cursor) {
    __shared__ int s[1024];
    int tid = threadIdx.x;
    int base = tid * 32;
    int sum = 0;
    for (int j = 0; j < 32; ++j) sum += counts[base + j];
    s[tid] = sum;
    __syncthreads();
    for (int off = 1; off < 1024; off <<= 1) {
        int v = (tid >= off) ? s[tid - off] : 0;
        __syncthreads();
        s[tid] += v;
        __syncthreads();
    }
    int run = s[tid] - sum;
    for (int j = 0; j < 32; ++j) {
        int c = counts[base + j];
        offsets[base + j] = run;
        cursor [base + j] = run;
        run += c;
    }
    if (tid == 1023) offsets[TT] = run;
}

__global__ __launch_bounds__(256) void k_fill(const int* __restrict__ tail_index,
                                              int* __restrict__ cursor,
                                              int* __restrict__ list) {
    int i = blockIdx.x * 256 + threadIdx.x;
    if (i < BNN) {
        int t = tail_index[i];
        int p = atomicAdd(&cursor[t], 1);
        list[p] = i;
    }
}

__device__ __forceinline__ double dot8(const float4 a0, const float4 a1,
                                       const float4 wa, const float4 wb) {
    return (double)a0.x*(double)wa.x + (double)a0.y*(double)wa.y
         + (double)a0.z*(double)wa.z + (double)a0.w*(double)wa.w
         + (double)a1.x*(double)wb.x + (double)a1.y*(double)wb.y
         + (double)a1.z*(double)wb.z + (double)a1.w*(double)wb.w;
}

// ---------------- Phase A: streaming att + agg_att ----------------
// 16-lane groups (8 dims/lane): 4 rows per wave-iteration, 4-step butterfly,
// one SIMT exp+div serves 4 rows. 8 software-pipelined iterations per wave:
// next iteration's loads issue before the current f64 chain.
#define AITER 8
__global__ __launch_bounds__(256) void k_att(const float* __restrict__ r_n,
                                             const float* __restrict__ t_n,
                                             const float* __restrict__ tm_n,
                                             const float* __restrict__ hidden,
                                             const float* __restrict__ Wrule,
                                             const float* __restrict__ brule,
                                             const int* __restrict__ tail_index,
                                             const double* __restrict__ w_all,
                                             const double* __restrict__ c_all,
                                             double* __restrict__ attArr,
                                             double* __restrict__ agg_att) {
    const int tid  = threadIdx.x;
    const int wv   = tid >> 6;          // wave 0..3
    const int lane = tid & 63;
    const int g    = lane >> 4;         // group 0..3
    const int s    = lane & 15;
    const int d0   = s * 8;
    const int rowBase = blockIdx.x * (16 * AITER);   // 128 rows per block
    const int b = rowBase >> 13;        // one batch per block (128 | 8192)

    // per-lane weights (f32 values, f64 accumulate — validated R4+)
    const double* w = w_all + b * 3 * DD;
    float4 w0a, w0b, w1a, w1b, w2a, w2b;
    w0a.x=(float)w[d0+0]; w0a.y=(float)w[d0+1]; w0a.z=(float)w[d0+2]; w0a.w=(float)w[d0+3];
    w0b.x=(float)w[d0+4]; w0b.y=(float)w[d0+5]; w0b.z=(float)w[d0+6]; w0b.w=(float)w[d0+7];
    w1a.x=(float)w[DD+d0+0]; w1a.y=(float)w[DD+d0+1]; w1a.z=(float)w[DD+d0+2]; w1a.w=(float)w[DD+d0+3];
    w1b.x=(float)w[DD+d0+4]; w1b.y=(float)w[DD+d0+5]; w1b.z=(float)w[DD+d0+6]; w1b.w=(float)w[DD+d0+7];
    w2a.x=(float)w[2*DD+d0+0]; w2a.y=(float)w[2*DD+d0+1]; w2a.z=(float)w[2*DD+d0+2]; w2a.w=(float)w[2*DD+d0+3];
    w2b.x=(float)w[2*DD+d0+4]; w2b.y=(float)w[2*DD+d0+5]; w2b.z=(float)w[2*DD+d0+6]; w2b.w=(float)w[2*DD+d0+7];
    const float4 wra = *(const float4*)(Wrule + d0);
    const float4 wrb = *(const float4*)(Wrule + d0 + 4);
    const double cb = c_all[b];
    const double br = (double)brule[0];

    // prologue: load iteration 0
    int rowC = rowBase + wv * 4 + g;
    long long baseC = (long long)rowC * DD + d0;
    float4 Ar0 = *(const float4*)(r_n    + baseC);
    float4 Ar1 = *(const float4*)(r_n    + baseC + 4);
    float4 At0 = *(const float4*)(t_n    + baseC);
    float4 At1 = *(const float4*)(t_n    + baseC + 4);
    float4 Am0 = *(const float4*)(tm_n   + baseC);
    float4 Am1 = *(const float4*)(tm_n   + baseC + 4);
    float4 Ah0 = *(const float4*)(hidden + baseC);
    float4 Ah1 = *(const float4*)(hidden + baseC + 4);
    int tC = tail_index[rowC];

    #pragma unroll
    for (int i = 0; i < AITER; ++i) {
        // issue next iteration's loads BEFORE the dependent chain
        int rowN = rowC; int tN = tC;
        float4 Br0=Ar0, Br1=Ar1, Bt0=At0, Bt1=At1, Bm0=Am0, Bm1=Am1, Bh0=Ah0, Bh1=Ah1;
        if (i + 1 < AITER) {
            rowN = rowBase + (i + 1) * 16 + wv * 4 + g;
            long long bn = (long long)rowN * DD + d0;
            Br0 = *(const float4*)(r_n    + bn);
            Br1 = *(const float4*)(r_n    + bn + 4);
            Bt0 = *(const float4*)(t_n    + bn);
            Bt1 = *(const float4*)(t_n    + bn + 4);
            Bm0 = *(const float4*)(tm_n   + bn);
            Bm1 = *(const float4*)(tm_n   + bn + 4);
            Bh0 = *(const float4*)(hidden + bn);
            Bh1 = *(const float4*)(hidden + bn + 4);
            tN  = tail_index[rowN];
        }

        double z1 = dot8(Ar0, Ar1, w0a, w0b)
                  + dot8(At0, At1, w1a, w1b)
                  + dot8(Am0, Am1, w2a, w2b);
        double z2 = dot8(Ah0, Ah1, wra, wrb);
        #pragma unroll
        for (int o = 1; o < 16; o <<= 1) {
            z1 += __shfl_xor(z1, o);
            z2 += __shfl_xor(z2, o);
        }
        // parity exp dedup within each 16-lane group
        double x   = (lane & 1) ? (z2 + br) : (z1 + cb);
        double ex  = exp(-x);
        double exo = __shfl_xor(ex, 1);
        double att = 0.5 * (2.0 + ex + exo) / ((1.0 + ex) * (1.0 + exo));
        if (s == 0) {
            attArr[rowC] = att;
            unsafeAtomicAdd(&agg_att[tC], att);
        }

        // rotate
        rowC = rowN; tC = tN;
        Ar0=Br0; Ar1=Br1; At0=Bt0; At1=Bt1; Am0=Bm0; Am1=Bm1; Ah0=Bh0; Ah1=Bh1;
    }
}

// Per-batch exact top-k: bitonic sort of M=2048 (value desc, index asc).
__global__ __launch_bounds__(1024) void k_topk(const double* __restrict__ agg_att,
                                               const int* __restrict__ tail_nodes,
                                               int* __restrict__ idx_out,
                                               float* __restrict__ out_nodes) {
    int b = blockIdx.x;
    __shared__ double v[MM];
    __shared__ int    id[MM];
    for (int i = threadIdx.x; i < MM; i += blockDim.x) {
        v[i]  = agg_att[b*MM + i];
        id[i] = i;
    }
    __syncthreads();
    for (int k = 2; k <= MM; k <<= 1) {
        for (int j = k >> 1; j > 0; j >>= 1) {
            for (int i = threadIdx.x; i < MM; i += blockDim.x) {
                int ixj = i ^ j;
                if (ixj > i) {
                    double va = v[i], vb = v[ixj];
                    int    ia = id[i], ib = id[ixj];
                    bool aBeforeB = (va > vb) || (va == vb && ia < ib);
                    bool wantBefore = ((i & k) == 0);
                    if (wantBefore != aBeforeB) {
                        v[i] = vb; v[ixj] = va;
                        id[i] = ib; id[ixj] = ia;
                    }
                }
            }
            __syncthreads();
        }
    }
    for (int r = threadIdx.x; r < TOPKK; r += blockDim.x) {
        int t = b * MM + id[r];
        idx_out[b*TOPKK + r] = t;
        out_nodes[(b*TOPKK + r)*2 + 0] = (float)tail_nodes[t*3 + 1];
        out_nodes[(b*TOPKK + r)*2 + 1] = (float)tail_nodes[t*3 + 2];
    }
}

// ---------------- Phase C: aggregate ONLY winning segments ----------------
__global__ __launch_bounds__(256) void k_aggW(const float* __restrict__ r_n,
                                              const float* __restrict__ tm_n,
                                              const float* __restrict__ hidden,
                                              const float* __restrict__ q_head,
                                              const float* __restrict__ tail_emd,
                                              const int* __restrict__ offsets,
                                              const int* __restrict__ list,
                                              const double* __restrict__ attArr,
                                              const int* __restrict__ idx_ws,
                                              float* __restrict__ taw,
                                              float* __restrict__ out_hid) {
    const int hw = threadIdx.x >> 5;
    const int sl = threadIdx.x & 31;
    const int d0 = 4 * sl;
    const int wi = blockIdx.x * 8 + hw;      // winner index, rank order
    const int t  = idx_ws[wi];
    const int b  = t >> 11;                  // t / M

    const float4 qh = *(const float4*)(q_head + b*DD + d0);
    const int start = offsets[t];
    const int end   = offsets[t + 1];

    float p0 = 0.f, p1 = 0.f, p2 = 0.f, p3 = 0.f;
    float h0 = 0.f, h1 = 0.f, h2 = 0.f, h3 = 0.f;
    double asum = 0.0;

    for (int e = start; e < end; ++e) {
        int row = list[e];
        long long base = (long long)row * DD + d0;
        float4 rv = *(const float4*)(r_n    + base);
        float4 mv = *(const float4*)(tm_n   + base);
        float4 hv = *(const float4*)(hidden + base);
        double attd = attArr[row];
        float  att  = (float)attd;
        p0 += att * (rv.x + mv.x); p1 += att * (rv.y + mv.y);
        p2 += att * (rv.z + mv.z); p3 += att * (rv.w + mv.w);
        h0 += hv.x; h1 += hv.y; h2 += hv.z; h3 += hv.w;
        asum += attd;
    }

    float A = (float)asum;
    long long ot = (long long)t  * DD + d0;
    long long ow = (long long)wi * DD + d0;
    float4 te = *(const float4*)(tail_emd + ot);
    float4 ta;
    ta.x = te.x + A*qh.x + p0; ta.y = te.y + A*qh.y + p1;
    ta.z = te.z + A*qh.z + p2; ta.w = te.w + A*qh.w + p3;
    *(float4*)(taw + ow) = ta;
    float4 nh; nh.x = h0; nh.y = h1; nh.z = h2; nh.w = h3;
    *(float4*)(out_hid + ow) = nh;
}

// Epilogue: emd = taw @ Wout + bout (compact, contiguous rows).
#define ROWS_PER_BLK 8
__global__ __launch_bounds__(128) void k_out(const float* __restrict__ taw,
                                             const float* __restrict__ Wout,
                                             const float* __restrict__ bout,
                                             float* __restrict__ out_emd) {
    int c = threadIdx.x;
    int pair0 = blockIdx.x * ROWS_PER_BLK;
    __shared__ float a_s[ROWS_PER_BLK][DD];
    #pragma unroll
    for (int j = 0; j < ROWS_PER_BLK; ++j)
        a_s[j][c] = taw[(long long)(pair0 + j) * DD + c];
    __syncthreads();
    float acc[ROWS_PER_BLK];
    float bc = bout[c];
    #pragma unroll
    for (int j = 0; j < ROWS_PER_BLK; ++j) acc[j] = bc;
    for (int d = 0; d < DD; ++d) {
        float wv = Wout[d*DD + c];
        #pragma unroll
        for (int j = 0; j < ROWS_PER_BLK; ++j)
            acc[j] = fmaf(a_s[j][d], wv, acc[j]);
    }
    #pragma unroll
    for (int j = 0; j < ROWS_PER_BLK; ++j)
        out_emd[(long long)(pair0 + j) * DD + c] = acc[j];
}

extern "C" void kernel_launch(void* const* d_in, const int* in_sizes, int n_in,
                              void* d_out, int out_size, void* d_ws, size_t ws_size,
                              hipStream_t stream) {
    const float* q_head   = (const float*)d_in[0];
    const float* q_rel    = (const float*)d_in[1];
    const float* q_time   = (const float*)d_in[2];
    const float* r_n      = (const float*)d_in[3];
    const float* t_n      = (const float*)d_in[4];
    const float* tm_n     = (const float*)d_in[5];
    const float* hidden   = (const float*)d_in[6];
    const float* tail_emd = (const float*)d_in[7];
    const int*   tail_index = (const int*)d_in[8];
    const int*   tail_nodes = (const int*)d_in[9];
    const float* Wq   = (const float*)d_in[10];
    const float* bq   = (const float*)d_in[11];
    const float* Wa   = (const float*)d_in[12];
    const float* ba   = (const float*)d_in[13];
    const float* Watt = (const float*)d_in[14];
    const float* batt = (const float*)d_in[15];
    const float* Wrule = (const float*)d_in[16];
    const float* brule = (const float*)d_in[17];
    const float* Wout = (const float*)d_in[18];
    const float* bout = (const float*)d_in[19];

    char* ws = (char*)d_ws;
    float*  taw     = (float*) (ws + WS_TAW);
    int*    counts  = (int*)   (ws + WS_COUNTS);
    double* agg_att = (double*)(ws + WS_AGG);
    double* w_all   = (double*)(ws + WS_W);
    double* c_all   = (double*)(ws + WS_C);
    int*    idx_ws  = (int*)   (ws + WS_IDX);
    int*    offsets = (int*)   (ws + WS_OFFSETS);
    int*    cursor  = (int*)   (ws + WS_CURSOR);
    int*    list    = (int*)   (ws + WS_LIST);
    double* attArr  = (double*)(ws + WS_ATT);

    float* out       = (float*)d_out;
    float* out_nodes = out;                      // B*TOPK*2
    float* out_emd   = out + BB*TOPKK*2;         // B*TOPK*D
    float* out_hid   = out_emd + BB*TOPKK*DD;    // B*TOPK*D

    // counts (128KB) + agg_att (256KB) are adjacent: one memset
    hipMemsetAsync(counts, 0, TT*sizeof(int) + TT*sizeof(double), stream);
    hipLaunchKernelGGL(k_prep, dim3(BB), dim3(DD), 0, stream,
                       q_head, q_rel, q_time, Wq, bq, Wa, ba, Watt, batt,
                       w_all, c_all);
    hipLaunchKernelGGL(k_count, dim3(BNN/256), dim3(256), 0, stream,
                       tail_index, counts);
    hipLaunchKernelGGL(k_scan, dim3(1), dim3(1024), 0, stream,
                       counts, offsets, cursor);
    hipLaunchKernelGGL(k_fill, dim3(BNN/256), dim3(256), 0, stream,
                       tail_index, cursor, list);
    hipLaunchKernelGGL(k_att, dim3(BNN/(16*AITER)), dim3(256), 0, stream,
                       r_n, t_n, tm_n, hidden, Wrule, brule,
                       tail_index, w_all, c_all, attArr, agg_att);
    hipLaunchKernelGGL(k_topk, dim3(BB), dim3(1024), 0, stream,
                       agg_att, tail_nodes, idx_ws, out_nodes);
    hipLaunchKernelGGL(k_aggW, dim3(WINS/8), dim3(256), 0, stream,
                       r_n, tm_n, hidden, q_head, tail_emd,
                       offsets, list, attArr, idx_ws, taw, out_hid);
    hipLaunchKernelGGL(k_out, dim3(WINS/ROWS_PER_BLK), dim3(DD), 0, stream,
                       taw, Wout, bout, out_emd);
}